// Round 11
// baseline (1268.039 us; speedup 1.0000x reference)
//
#include <hip/hip_runtime.h>
#include <math.h>

#define N_PIX 4096  // H*W = 64*64
#define BATCH 4
#define LOG2E 1.4426950408889634f

typedef __bf16 bf16x8 __attribute__((ext_vector_type(8)));
typedef __bf16 bf16x4v __attribute__((ext_vector_type(4)));
typedef float f32x4 __attribute__((ext_vector_type(4)));

// ---------------------------------------------------------------------------
// Fused spectral norms: one block per layer, 1024 threads (16 waves).
// ---------------------------------------------------------------------------
struct SigP {
    const float* W[5];
    const float* u[5];
    int O[5];
    int C[5];
};

__global__ __launch_bounds__(1024)
void sigma_all(SigP p, float* __restrict__ out_inv) {
    __shared__ float ush[512];
    __shared__ float vsh[512];
    __shared__ float vpart[16 * 512];
    __shared__ float redl[1024];
    int L = blockIdx.x;
    const float* W = p.W[L];
    const float* u = p.u[L];
    int O = p.O[L], C = p.C[L];
    int t = threadIdx.x;
    int w = t >> 6, lane = t & 63;

    for (int i = t; i < O; i += 1024) ush[i] = u[i];
    __syncthreads();

    int o_beg = (O * w) >> 4, o_end = (O * (w + 1)) >> 4;
    for (int c = lane; c < C; c += 64) {
        float a = 0.f;
        for (int o = o_beg; o < o_end; ++o) a += W[(size_t)o * C + c] * ush[o];
        vpart[w * 512 + c] = a;
    }
    __syncthreads();

    float nn = 0.f;
    for (int c = t; c < C; c += 1024) {
        float s = 0.f;
        #pragma unroll
        for (int w2 = 0; w2 < 16; ++w2) s += vpart[w2 * 512 + c];
        vsh[c] = s;
        nn += s * s;
    }
    redl[t] = nn;
    __syncthreads();
    for (int s = 512; s > 0; s >>= 1) {
        if (t < s) redl[t] += redl[t + s];
        __syncthreads();
    }
    float nrm2 = redl[0];
    __syncthreads();
    float rinv = 1.f / (sqrtf(nrm2) + 1e-12f);

    float sq = 0.f;
    for (int o = w; o < O; o += 16) {
        float a = 0.f;
        for (int c = lane; c < C; c += 64) a += W[(size_t)o * C + c] * vsh[c];
        #pragma unroll
        for (int off = 1; off < 64; off <<= 1) a += __shfl_xor(a, off);
        if (lane == 0) sq += a * a;
    }
    if (lane == 0) redl[w] = sq;
    __syncthreads();
    if (t == 0) {
        float ns2raw = 0.f;
        #pragma unroll
        for (int i = 0; i < 16; ++i) ns2raw += redl[i];
        float ns2 = rinv * rinv * ns2raw;
        float sg = ns2 / (sqrtf(ns2) + 1e-12f);
        out_inv[L] = 1.f / sg;
    }
}

// ---------------------------------------------------------------------------
// Weight split: (O,C) fp32 * iv * scale -> (O, 2C) bf16  [hi | lo].
// ---------------------------------------------------------------------------
__global__ __launch_bounds__(256)
void wsplit_kernel(const float* __restrict__ W, const float* __restrict__ iv,
                   float scale, int C, __bf16* __restrict__ out) {
    int o = blockIdx.x;
    float s = (iv ? iv[0] : 1.f) * scale;
    for (int c = threadIdx.x; c < C; c += 256) {
        float wv = W[(size_t)o * C + c] * s;
        __bf16 hi = (__bf16)wv;
        float lo = wv - (float)hi;
        out[(size_t)o * 2 * C + c] = hi;
        out[(size_t)o * 2 * C + C + c] = (__bf16)lo;
    }
}

// ---------------------------------------------------------------------------
// L1 only: fp32 VALU conv (C=6). x (B,C,N) -> out (B,O,N) fp32.
// ---------------------------------------------------------------------------
__global__ __launch_bounds__(256)
void conv_f32_kernel(const float* __restrict__ x, const float* __restrict__ W,
                     const float* __restrict__ bias, const float* __restrict__ sig,
                     float* __restrict__ out, int C, int O, int lrelu) {
    __shared__ float Ws[16][68];
    __shared__ float Xs[16][68];
    int t = threadIdx.x;
    int tx = t & 15, ty = t >> 4;
    int b = blockIdx.z;
    int n0 = blockIdx.x * 64, o0 = blockIdx.y * 64;
    float acc[4][4] = {};
    const float* xb = x + (size_t)b * C * N_PIX;
    for (int c0 = 0; c0 < C; c0 += 16) {
        #pragma unroll
        for (int i = 0; i < 4; ++i) {
            int e = t + i * 256;
            int o = e >> 4, c = e & 15;
            float wv = 0.f;
            if (o0 + o < O && c0 + c < C) wv = W[(size_t)(o0 + o) * C + c0 + c];
            Ws[c][o] = wv;
        }
        #pragma unroll
        for (int i = 0; i < 4; ++i) {
            int e = t + i * 256;
            int c = e >> 6, n = e & 63;
            float xv = 0.f;
            if (c0 + c < C) xv = xb[(size_t)(c0 + c) * N_PIX + n0 + n];
            Xs[c][n] = xv;
        }
        __syncthreads();
        #pragma unroll
        for (int cc = 0; cc < 16; ++cc) {
            float4 wv = *(const float4*)&Ws[cc][ty * 4];
            float4 xv = *(const float4*)&Xs[cc][tx * 4];
            float wa[4] = {wv.x, wv.y, wv.z, wv.w};
            float xa[4] = {xv.x, xv.y, xv.z, xv.w};
            #pragma unroll
            for (int i = 0; i < 4; ++i)
                #pragma unroll
                for (int j = 0; j < 4; ++j)
                    acc[i][j] += wa[i] * xa[j];
        }
        __syncthreads();
    }
    float ivv = sig ? sig[0] : 1.f;
    for (int i = 0; i < 4; ++i) {
        int o = o0 + ty * 4 + i;
        if (o >= O) break;
        float bv = bias[o];
        float vres[4];
        #pragma unroll
        for (int j = 0; j < 4; ++j) {
            float v = acc[i][j] * ivv + bv;
            if (lrelu) v = (v > 0.f) ? v : 0.1f * v;
            vres[j] = v;
        }
        *(float4*)&out[((size_t)b * O + o) * N_PIX + n0 + tx * 4] =
            make_float4(vres[0], vres[1], vres[2], vres[3]);
    }
}

// ---------------------------------------------------------------------------
// Transpose+split: (B,64,N) fp32 -> (B,N,128) bf16 [hi(64)|lo(64)].
// ---------------------------------------------------------------------------
__global__ __launch_bounds__(256)
void tsplit64_kernel(const float* __restrict__ in, __bf16* __restrict__ out) {
    __shared__ float tile[64 * 65];
    int t = threadIdx.x;
    int n0 = blockIdx.x * 64, b = blockIdx.y;
    for (int e = t; e < 64 * 64; e += 256) {
        int c = e >> 6, n = e & 63;
        tile[n * 65 + c] = in[((size_t)b * 64 + c) * N_PIX + n0 + n];
    }
    __syncthreads();
    for (int e = t; e < 64 * 64; e += 256) {
        int n = e >> 6, c = e & 63;
        float v = tile[n * 65 + c];
        __bf16 hi = (__bf16)v;
        size_t base = ((size_t)b * N_PIX + n0 + n) * 128;
        out[base + c] = hi;
        out[base + 64 + c] = (__bf16)(v - (float)hi);
    }
}

// ---------------------------------------------------------------------------
// Split-bf16 MFMA 1x1 conv (unchanged).
// ---------------------------------------------------------------------------
template <int WO, int WN, int MODE, int IN_F32, int LRELU>
__global__ __launch_bounds__(256)
void mfma_conv(const void* __restrict__ xt, const __bf16* __restrict__ wsp,
               const float* __restrict__ bias, float bscale,
               void* __restrict__ outp, int C, int O) {
    constexpr int NT_BLK = WN * 128;
    __shared__ __bf16 Ws[WO * 32 * 72];
    __shared__ __bf16 Xs[NT_BLK * 72];
    int t = threadIdx.x;
    int lane = t & 63, w = t >> 6;
    int l15 = lane & 15, quad = lane >> 4;
    int wo = w / WN, wn = w % WN;
    int b = blockIdx.z;
    int n0b = blockIdx.x * NT_BLK, o0b = blockIdx.y * WO * 32;

    f32x4 acc[2][8] = {};

    for (int c0 = 0; c0 < C; c0 += 32) {
        __syncthreads();
        for (int e = t; e < WO * 32 * 8; e += 256) {
            int row = e >> 3, part = e & 7;
            size_t src = (size_t)(o0b + row) * 2 * C +
                         (part < 4 ? c0 + part * 8 : C + c0 + (part - 4) * 8);
            int dst = row * 72 + (part < 4 ? part * 8 : 32 + (part - 4) * 8);
            *(uint4*)&Ws[dst] = *(const uint4*)&wsp[src];
        }
        if (IN_F32) {
            const float* xf = (const float*)xt;
            for (int e = t; e < NT_BLK * 8; e += 256) {
                int row = e >> 3, part = e & 7;
                float4 v = *(const float4*)&xf[((size_t)b * N_PIX + n0b + row) * C + c0 + part * 4];
                bf16x4v hi, lo;
                float va[4] = {v.x, v.y, v.z, v.w};
                #pragma unroll
                for (int j = 0; j < 4; ++j) {
                    hi[j] = (__bf16)va[j];
                    lo[j] = (__bf16)(va[j] - (float)hi[j]);
                }
                *(bf16x4v*)&Xs[row * 72 + part * 4] = hi;
                *(bf16x4v*)&Xs[row * 72 + 32 + part * 4] = lo;
            }
        } else {
            const __bf16* xb = (const __bf16*)xt;
            for (int e = t; e < NT_BLK * 8; e += 256) {
                int row = e >> 3, part = e & 7;
                size_t src = ((size_t)b * N_PIX + n0b + row) * 2 * C +
                             (part < 4 ? c0 + part * 8 : C + c0 + (part - 4) * 8);
                int dst = row * 72 + (part < 4 ? part * 8 : 32 + (part - 4) * 8);
                *(uint4*)&Xs[dst] = *(const uint4*)&xb[src];
            }
        }
        __syncthreads();

        bf16x8 ah[2], al[2];
        #pragma unroll
        for (int mf = 0; mf < 2; ++mf) {
            int base = (wo * 32 + mf * 16 + l15) * 72 + quad * 8;
            ah[mf] = *(const bf16x8*)&Ws[base];
            al[mf] = *(const bf16x8*)&Ws[base + 32];
        }
        #pragma unroll
        for (int nt = 0; nt < 8; ++nt) {
            int bbase = (wn * 128 + nt * 16 + l15) * 72 + quad * 8;
            bf16x8 bh = *(const bf16x8*)&Xs[bbase];
            bf16x8 bl = *(const bf16x8*)&Xs[bbase + 32];
            #pragma unroll
            for (int mf = 0; mf < 2; ++mf) {
                acc[mf][nt] = __builtin_amdgcn_mfma_f32_16x16x32_bf16(ah[mf], bh, acc[mf][nt], 0, 0, 0);
                acc[mf][nt] = __builtin_amdgcn_mfma_f32_16x16x32_bf16(ah[mf], bl, acc[mf][nt], 0, 0, 0);
                acc[mf][nt] = __builtin_amdgcn_mfma_f32_16x16x32_bf16(al[mf], bh, acc[mf][nt], 0, 0, 0);
            }
        }
    }

    float bv[2][4];
    #pragma unroll
    for (int mf = 0; mf < 2; ++mf)
        #pragma unroll
        for (int r = 0; r < 4; ++r)
            bv[mf][r] = bias[o0b + wo * 32 + mf * 16 + quad * 4 + r] * bscale;

    #pragma unroll
    for (int mf = 0; mf < 2; ++mf)
        #pragma unroll
        for (int nt = 0; nt < 8; ++nt) {
            int n = n0b + wn * 128 + nt * 16 + l15;
            float val[4];
            #pragma unroll
            for (int r = 0; r < 4; ++r) {
                float v = acc[mf][nt][r] + bv[mf][r];
                if (LRELU) v = (v > 0.f) ? v : 0.1f * v;
                val[r] = v;
            }
            int obase = o0b + wo * 32 + mf * 16 + quad * 4;
            if (MODE == 1) {
                __bf16* ob = (__bf16*)outp;
                #pragma unroll
                for (int r = 0; r < 4; ++r)
                    ob[((size_t)b * O + obase + r) * N_PIX + n] = (__bf16)val[r];
            } else if (MODE == 2) {
                __bf16* ob = (__bf16*)outp;
                bf16x4v hv, lv;
                #pragma unroll
                for (int r = 0; r < 4; ++r) {
                    hv[r] = (__bf16)val[r];
                    lv[r] = (__bf16)(val[r] - (float)hv[r]);
                }
                size_t rb = ((size_t)b * N_PIX + n) * 2 * O + obase;
                *(bf16x4v*)&ob[rb] = hv;
                *(bf16x4v*)&ob[rb + O] = lv;
            } else {  // MODE 4
                __bf16* ob = (__bf16*)outp;
                bf16x4v hv;
                #pragma unroll
                for (int r = 0; r < 4; ++r) hv[r] = (__bf16)val[r];
                *(bf16x4v*)&ob[((size_t)b * N_PIX + n) * O + obase] = hv;
            }
        }
}

// ---------------------------------------------------------------------------
// Attention kernel 1/3: S[b,q,k] raw scores (exp2-domain), bf16.
// ---------------------------------------------------------------------------
template <int CQ>
__global__ __launch_bounds__(256)
void s_gemm(const __bf16* __restrict__ qt, const __bf16* __restrict__ kt,
            __bf16* __restrict__ S) {
    constexpr int NKK = CQ / 32;
    __shared__ __bf16 Ss[128 * 136];
    int t = threadIdx.x;
    int lane = t & 63, w = t >> 6;
    int l15 = lane & 15, quad = lane >> 4;
    int k0 = blockIdx.x * 128, q0 = blockIdx.y * 128, b = blockIdx.z;

    bf16x8 kf[2][NKK], qf[8][NKK];
    #pragma unroll
    for (int mf = 0; mf < 2; ++mf)
        #pragma unroll
        for (int kk = 0; kk < NKK; ++kk)
            kf[mf][kk] = *(const bf16x8*)&kt[((size_t)b * N_PIX + k0 + w * 32 + mf * 16 + l15) * CQ + kk * 32 + quad * 8];
    #pragma unroll
    for (int nt = 0; nt < 8; ++nt)
        #pragma unroll
        for (int kk = 0; kk < NKK; ++kk)
            qf[nt][kk] = *(const bf16x8*)&qt[((size_t)b * N_PIX + q0 + nt * 16 + l15) * CQ + kk * 32 + quad * 8];

    f32x4 acc[2][8] = {};
    #pragma unroll
    for (int kk = 0; kk < NKK; ++kk)
        #pragma unroll
        for (int mf = 0; mf < 2; ++mf)
            #pragma unroll
            for (int nt = 0; nt < 8; ++nt)
                acc[mf][nt] = __builtin_amdgcn_mfma_f32_16x16x32_bf16(kf[mf][kk], qf[nt][kk], acc[mf][nt], 0, 0, 0);

    #pragma unroll
    for (int mf = 0; mf < 2; ++mf)
        #pragma unroll
        for (int nt = 0; nt < 8; ++nt) {
            bf16x4v pk;
            #pragma unroll
            for (int r = 0; r < 4; ++r) pk[r] = (__bf16)acc[mf][nt][r];
            *(bf16x4v*)&Ss[(nt * 16 + l15) * 136 + w * 32 + mf * 16 + quad * 4] = pk;
        }
    __syncthreads();
    int ql = t >> 1, kh = (t & 1) * 64;
    size_t row = ((size_t)b * N_PIX + q0 + ql) * N_PIX + k0 + kh;
    #pragma unroll
    for (int j = 0; j < 8; ++j)
        *(uint4*)&S[row + j * 8] = *(const uint4*)&Ss[ql * 136 + kh + j * 8];
}

// ---------------------------------------------------------------------------
// Attention kernel 2/3: in-place row softmax on S (exp2 domain), ONCE.
// One wave per 4096-key row; 4 rows/block.
// ---------------------------------------------------------------------------
__global__ __launch_bounds__(256)
void softmax_rows(__bf16* __restrict__ S) {
    int t = threadIdx.x;
    int lane = t & 63, w = t >> 6;
    __bf16* Sr = S + ((size_t)blockIdx.x * 4 + w) * N_PIX;
    bf16x8 v[8];
    #pragma unroll
    for (int j = 0; j < 8; ++j) v[j] = *(const bf16x8*)&Sr[j * 512 + lane * 8];
    float m = -1e30f;
    #pragma unroll
    for (int j = 0; j < 8; ++j)
        #pragma unroll
        for (int e = 0; e < 8; ++e) m = fmaxf(m, (float)v[j][e]);
    #pragma unroll
    for (int off = 1; off < 64; off <<= 1) m = fmaxf(m, __shfl_xor(m, off));
    float s = 0.f;
    #pragma unroll
    for (int j = 0; j < 8; ++j)
        #pragma unroll
        for (int e = 0; e < 8; ++e) {
            float p = exp2f((float)v[j][e] - m);
            s += p;
            v[j][e] = (__bf16)p;
        }
    #pragma unroll
    for (int off = 1; off < 64; off <<= 1) s += __shfl_xor(s, off);
    float il = 1.f / s;
    #pragma unroll
    for (int j = 0; j < 8; ++j) {
        #pragma unroll
        for (int e = 0; e < 8; ++e) v[j][e] = (__bf16)((float)v[j][e] * il);
        *(bf16x8*)&Sr[j * 512 + lane * 8] = v[j];
    }
}

// ---------------------------------------------------------------------------
// Attention kernel 3/3: LDS-FREE, BARRIER-FREE PV GEMM.
// O[b,q,c] = gamma * sum_k P[b,q,k] V[b,c,k] + residual.
// A-frags (P rows) and B-frags (V rows) loaded straight from global:
//   A: P[(q0+w*32+mf*16+l15)*N + k0+kk*32+quad*8]  (16 rows x 64B segments,
//      shared across the 8 c-blocks -> L2, XCD-pinned)
//   B: V[(c0+nt*16+l15)*N + k0+kk*32+quad*8]       (same rows all 4 waves -> L1)
// Grid 1024 = 8 cblk x 128 pair; bid%8==pair%8 pins P-slab sharers to one XCD.
// ---------------------------------------------------------------------------
template <int NT>
__global__ __launch_bounds__(256)
void pv_direct(const __bf16* __restrict__ P, const __bf16* __restrict__ vg,
               const __bf16* __restrict__ xin2, const float* __restrict__ gamma,
               float* __restrict__ out, int C) {
    int t = threadIdx.x;
    int lane = t & 63, w = t >> 6;
    int l15 = lane & 15, quad = lane >> 4;
    int bid = blockIdx.x;
    int pair = bid & 127, cblk = bid >> 7;
    int qi = pair >> 2, b = pair & 3;
    int q0 = qi * 128, c0 = cblk * NT * 16;

    const __bf16* Pr0 = P + ((size_t)b * N_PIX + q0 + w * 32 + l15) * N_PIX + quad * 8;
    const __bf16* Pr1 = Pr0 + (size_t)16 * N_PIX;
    const __bf16* Vr[NT];
    #pragma unroll
    for (int nt = 0; nt < NT; ++nt)
        Vr[nt] = vg + ((size_t)b * C + c0 + nt * 16 + l15) * N_PIX + quad * 8;

    f32x4 acc[2][NT] = {};

    for (int k0 = 0; k0 < N_PIX; k0 += 64) {
        bf16x8 pf[2][2], vf[NT][2];
        #pragma unroll
        for (int kk = 0; kk < 2; ++kk) {
            pf[0][kk] = *(const bf16x8*)&Pr0[k0 + kk * 32];
            pf[1][kk] = *(const bf16x8*)&Pr1[k0 + kk * 32];
            #pragma unroll
            for (int nt = 0; nt < NT; ++nt)
                vf[nt][kk] = *(const bf16x8*)&Vr[nt][k0 + kk * 32];
        }
        #pragma unroll
        for (int kk = 0; kk < 2; ++kk)
            #pragma unroll
            for (int nt = 0; nt < NT; ++nt) {
                acc[0][nt] = __builtin_amdgcn_mfma_f32_16x16x32_bf16(pf[0][kk], vf[nt][kk], acc[0][nt], 0, 0, 0);
                acc[1][nt] = __builtin_amdgcn_mfma_f32_16x16x32_bf16(pf[1][kk], vf[nt][kk], acc[1][nt], 0, 0, 0);
            }
    }

    float g = gamma[0];
    #pragma unroll
    for (int mf = 0; mf < 2; ++mf)
        #pragma unroll
        for (int r = 0; r < 4; ++r) {
            int q = q0 + w * 32 + mf * 16 + quad * 4 + r;
            size_t xrb = ((size_t)b * N_PIX + q) * 2 * C;
            size_t orb = ((size_t)b * N_PIX + q) * C;
            #pragma unroll
            for (int nt = 0; nt < NT; ++nt) {
                int c = c0 + nt * 16 + l15;
                float xr = (float)xin2[xrb + c] + (float)xin2[xrb + C + c];
                out[orb + c] = g * acc[mf][nt][r] + xr;
            }
        }
}

// ---------------------------------------------------------------------------
// L5: out[b,n] = lrelu(iv * dot(W5, h[b,n,:]) + b5).  h: (B,N,512) fp32.
// ---------------------------------------------------------------------------
__global__ __launch_bounds__(256)
void l5_kernel(const float* __restrict__ h, const float* __restrict__ W5,
               const float* __restrict__ b5, const float* __restrict__ sig,
               float* __restrict__ out) {
    int t = threadIdx.x;
    int lane = t & 63, w = t >> 6;
    int p = blockIdx.x * 4 + w;
    const float* row = h + (size_t)p * 512;
    float4 a0 = *(const float4*)&row[lane * 8];
    float4 a1 = *(const float4*)&row[lane * 8 + 4];
    float4 w0 = *(const float4*)&W5[lane * 8];
    float4 w1 = *(const float4*)&W5[lane * 8 + 4];
    float s = a0.x * w0.x + a0.y * w0.y + a0.z * w0.z + a0.w * w0.w +
              a1.x * w1.x + a1.y * w1.y + a1.z * w1.z + a1.w * w1.w;
    #pragma unroll
    for (int off = 1; off < 64; off <<= 1) s += __shfl_xor(s, off);
    if (lane == 0) {
        float v = sig[0] * s + b5[0];
        out[p] = (v > 0.f) ? v : 0.1f * v;
    }
}

// ---------------------------------------------------------------------------
// Launcher
// ---------------------------------------------------------------------------
extern "C" void kernel_launch(void* const* d_in, const int* in_sizes, int n_in,
                              void* d_out, int out_size, void* d_ws, size_t ws_size,
                              hipStream_t stream) {
    const float* x   = (const float*)d_in[0];
    const float* W1  = (const float*)d_in[1];
    const float* b1  = (const float*)d_in[2];
    const float* u1  = (const float*)d_in[3];
    const float* W2  = (const float*)d_in[4];
    const float* b2  = (const float*)d_in[5];
    const float* u2  = (const float*)d_in[6];
    const float* W3  = (const float*)d_in[7];
    const float* b3  = (const float*)d_in[8];
    const float* u3  = (const float*)d_in[9];
    const float* W4  = (const float*)d_in[10];
    const float* b4  = (const float*)d_in[11];
    const float* u4  = (const float*)d_in[12];
    const float* W5  = (const float*)d_in[13];
    const float* b5  = (const float*)d_in[14];
    const float* u5  = (const float*)d_in[15];
    const float* a1_qW = (const float*)d_in[16];
    const float* a1_qb = (const float*)d_in[17];
    const float* a1_kW = (const float*)d_in[18];
    const float* a1_kb = (const float*)d_in[19];
    const float* a1_vW = (const float*)d_in[20];
    const float* a1_vb = (const float*)d_in[21];
    const float* a1_g  = (const float*)d_in[22];
    const float* a2_qW = (const float*)d_in[23];
    const float* a2_qb = (const float*)d_in[24];
    const float* a2_kW = (const float*)d_in[25];
    const float* a2_kb = (const float*)d_in[26];
    const float* a2_vW = (const float*)d_in[27];
    const float* a2_vb = (const float*)d_in[28];
    const float* a2_g  = (const float*)d_in[29];

    float* ws = (float*)d_ws;
    const size_t NF = (size_t)BATCH * N_PIX;  // 16384
    float* sig    = ws;                       // 16
    float* h1     = ws + 16;                  // NF*64 fl
    float* slabC  = h1 + NF * 64;             // NF*512 fl
    float* slabS1 = slabC + NF * 512;         // NF*256 fl
    float* slabS2 = slabS1 + NF * 256;        // NF*512 fl
    float* qtf    = slabS2 + NF * 512;        // NF*32 fl
    float* ktf    = qtf + NF * 32;            // NF*32 fl
    float* wspf   = ktf + NF * 32;            // ~0.58M fl
    float* Sf     = wspf + 600000;            // S: NF*4096 bf16 = NF*2048 fl

    __bf16* h1t = (__bf16*)slabS1;            // (B,N,128)
    __bf16* h2t = (__bf16*)slabS2;            // (B,N,256)
    __bf16* h3t = (__bf16*)slabS1;            // (B,N,512)
    __bf16* h5t = (__bf16*)slabS2;            // (B,N,1024)
    float*  h4t = slabC;                      // (B,N,256) fp32
    __bf16* vb1 = (__bf16*)(slabC + NF * 256);// (B,256,N)
    float*  h6t = slabC;                      // (B,N,512) fp32
    __bf16* vb2 = (__bf16*)slabS1;            // (B,512,N)
    __bf16* qt  = (__bf16*)qtf;
    __bf16* ktb = (__bf16*)ktf;
    __bf16* wsp = (__bf16*)wspf;
    __bf16* Sbuf = (__bf16*)Sf;               // (B,4096,4096) bf16

    __bf16* wsL2  = wsp;            // 128*128
    __bf16* wsL3  = wsL2 + 16384;   // 256*256
    __bf16* wsL4  = wsL3 + 65536;   // 512*512
    __bf16* wsA1q = wsL4 + 262144;  // 32*512
    __bf16* wsA1k = wsA1q + 16384;
    __bf16* wsA1v = wsA1k + 16384;  // 256*512
    __bf16* wsA2q = wsA1v + 131072; // 64*1024
    __bf16* wsA2k = wsA2q + 65536;
    __bf16* wsA2v = wsA2k + 65536;  // 512*1024

    dim3 blk(256);

    SigP sp;
    sp.W[0] = W1; sp.u[0] = u1; sp.O[0] = 64;  sp.C[0] = 6;
    sp.W[1] = W2; sp.u[1] = u2; sp.O[1] = 128; sp.C[1] = 64;
    sp.W[2] = W3; sp.u[2] = u3; sp.O[2] = 256; sp.C[2] = 128;
    sp.W[3] = W4; sp.u[3] = u4; sp.O[3] = 512; sp.C[3] = 256;
    sp.W[4] = W5; sp.u[4] = u5; sp.O[4] = 1;   sp.C[4] = 512;
    sigma_all<<<dim3(5), dim3(1024), 0, stream>>>(sp, sig);

    wsplit_kernel<<<128, blk, 0, stream>>>(W2, sig + 1, 1.f, 64, wsL2);
    wsplit_kernel<<<256, blk, 0, stream>>>(W3, sig + 2, 1.f, 128, wsL3);
    wsplit_kernel<<<512, blk, 0, stream>>>(W4, sig + 3, 1.f, 256, wsL4);
    wsplit_kernel<<<32,  blk, 0, stream>>>(a1_qW, nullptr, LOG2E, 256, wsA1q);
    wsplit_kernel<<<32,  blk, 0, stream>>>(a1_kW, nullptr, 1.f, 256, wsA1k);
    wsplit_kernel<<<256, blk, 0, stream>>>(a1_vW, nullptr, 1.f, 256, wsA1v);
    wsplit_kernel<<<64,  blk, 0, stream>>>(a2_qW, nullptr, LOG2E, 512, wsA2q);
    wsplit_kernel<<<64,  blk, 0, stream>>>(a2_kW, nullptr, 1.f, 512, wsA2k);
    wsplit_kernel<<<512, blk, 0, stream>>>(a2_vW, nullptr, 1.f, 512, wsA2v);

    // L1 (fp32) + transpose/split
    conv_f32_kernel<<<dim3(64, 1, 4), blk, 0, stream>>>(x, W1, b1, sig + 0, h1, 6, 64, 1);
    tsplit64_kernel<<<dim3(64, 4), blk, 0, stream>>>(h1, h1t);

    // L2, L3 (split-MFMA)
    mfma_conv<4, 1, 2, 0, 1><<<dim3(32, 1, 4), blk, 0, stream>>>(h1t, wsL2, b2, 1.f, h2t, 64, 128);
    mfma_conv<4, 1, 2, 0, 1><<<dim3(32, 2, 4), blk, 0, stream>>>(h2t, wsL3, b3, 1.f, h3t, 128, 256);

    // attention 1 (C=256, Cq=32)
    mfma_conv<1, 4, 4, 0, 0><<<dim3(8, 1, 4), blk, 0, stream>>>(h3t, wsA1q, a1_qb, LOG2E, qt, 256, 32);
    mfma_conv<1, 4, 4, 0, 0><<<dim3(8, 1, 4), blk, 0, stream>>>(h3t, wsA1k, a1_kb, 1.f, ktb, 256, 32);
    mfma_conv<4, 1, 1, 0, 0><<<dim3(32, 2, 4), blk, 0, stream>>>(h3t, wsA1v, a1_vb, 1.f, vb1, 256, 256);
    s_gemm<32><<<dim3(32, 32, 4), blk, 0, stream>>>(qt, ktb, Sbuf);
    softmax_rows<<<dim3(4096), blk, 0, stream>>>(Sbuf);
    pv_direct<2><<<dim3(1024), blk, 0, stream>>>(Sbuf, vb1, h3t, a1_g, h4t, 256);

    // L4 (fp32-transposed input)
    mfma_conv<4, 1, 2, 1, 1><<<dim3(32, 4, 4), blk, 0, stream>>>(h4t, wsL4, b4, 1.f, h5t, 256, 512);

    // attention 2 (C=512, Cq=64)
    mfma_conv<2, 2, 4, 0, 0><<<dim3(16, 1, 4), blk, 0, stream>>>(h5t, wsA2q, a2_qb, LOG2E, qt, 512, 64);
    mfma_conv<2, 2, 4, 0, 0><<<dim3(16, 1, 4), blk, 0, stream>>>(h5t, wsA2k, a2_kb, 1.f, ktb, 512, 64);
    mfma_conv<4, 1, 1, 0, 0><<<dim3(32, 4, 4), blk, 0, stream>>>(h5t, wsA2v, a2_vb, 1.f, vb2, 512, 512);
    s_gemm<64><<<dim3(32, 32, 4), blk, 0, stream>>>(qt, ktb, Sbuf);
    softmax_rows<<<dim3(4096), blk, 0, stream>>>(Sbuf);
    pv_direct<4><<<dim3(1024), blk, 0, stream>>>(Sbuf, vb2, h5t, a2_g, h6t, 512);

    // L5
    l5_kernel<<<4096, blk, 0, stream>>>(h6t, W5, b5, sig + 4, (float*)d_out);
}

// Round 12
// 974.268 us; speedup vs baseline: 1.3015x; 1.3015x over previous
//
#include <hip/hip_runtime.h>
#include <math.h>

#define N_PIX 4096  // H*W = 64*64
#define BATCH 4
#define LOG2E 1.4426950408889634f

typedef __bf16 bf16x8 __attribute__((ext_vector_type(8)));
typedef __bf16 bf16x4v __attribute__((ext_vector_type(4)));
typedef float f32x4 __attribute__((ext_vector_type(4)));

// ---------------------------------------------------------------------------
// Fused spectral norms: one block per layer, 1024 threads (16 waves).
// ---------------------------------------------------------------------------
struct SigP {
    const float* W[5];
    const float* u[5];
    int O[5];
    int C[5];
};

__global__ __launch_bounds__(1024)
void sigma_all(SigP p, float* __restrict__ out_inv) {
    __shared__ float ush[512];
    __shared__ float vsh[512];
    __shared__ float vpart[16 * 512];
    __shared__ float redl[1024];
    int L = blockIdx.x;
    const float* W = p.W[L];
    const float* u = p.u[L];
    int O = p.O[L], C = p.C[L];
    int t = threadIdx.x;
    int w = t >> 6, lane = t & 63;

    for (int i = t; i < O; i += 1024) ush[i] = u[i];
    __syncthreads();

    int o_beg = (O * w) >> 4, o_end = (O * (w + 1)) >> 4;
    for (int c = lane; c < C; c += 64) {
        float a = 0.f;
        for (int o = o_beg; o < o_end; ++o) a += W[(size_t)o * C + c] * ush[o];
        vpart[w * 512 + c] = a;
    }
    __syncthreads();

    float nn = 0.f;
    for (int c = t; c < C; c += 1024) {
        float s = 0.f;
        #pragma unroll
        for (int w2 = 0; w2 < 16; ++w2) s += vpart[w2 * 512 + c];
        vsh[c] = s;
        nn += s * s;
    }
    redl[t] = nn;
    __syncthreads();
    for (int s = 512; s > 0; s >>= 1) {
        if (t < s) redl[t] += redl[t + s];
        __syncthreads();
    }
    float nrm2 = redl[0];
    __syncthreads();
    float rinv = 1.f / (sqrtf(nrm2) + 1e-12f);

    float sq = 0.f;
    for (int o = w; o < O; o += 16) {
        float a = 0.f;
        for (int c = lane; c < C; c += 64) a += W[(size_t)o * C + c] * vsh[c];
        #pragma unroll
        for (int off = 1; off < 64; off <<= 1) a += __shfl_xor(a, off);
        if (lane == 0) sq += a * a;
    }
    if (lane == 0) redl[w] = sq;
    __syncthreads();
    if (t == 0) {
        float ns2raw = 0.f;
        #pragma unroll
        for (int i = 0; i < 16; ++i) ns2raw += redl[i];
        float ns2 = rinv * rinv * ns2raw;
        float sg = ns2 / (sqrtf(ns2) + 1e-12f);
        out_inv[L] = 1.f / sg;
    }
}

// ---------------------------------------------------------------------------
// Weight split: (O,C) fp32 * iv * scale -> (O, 2C) bf16  [hi | lo].
// ---------------------------------------------------------------------------
__global__ __launch_bounds__(256)
void wsplit_kernel(const float* __restrict__ W, const float* __restrict__ iv,
                   float scale, int C, __bf16* __restrict__ out) {
    int o = blockIdx.x;
    float s = (iv ? iv[0] : 1.f) * scale;
    for (int c = threadIdx.x; c < C; c += 256) {
        float wv = W[(size_t)o * C + c] * s;
        __bf16 hi = (__bf16)wv;
        float lo = wv - (float)hi;
        out[(size_t)o * 2 * C + c] = hi;
        out[(size_t)o * 2 * C + C + c] = (__bf16)lo;
    }
}

// ---------------------------------------------------------------------------
// L1 only: fp32 VALU conv (C=6). x (B,C,N) -> out (B,O,N) fp32.
// ---------------------------------------------------------------------------
__global__ __launch_bounds__(256)
void conv_f32_kernel(const float* __restrict__ x, const float* __restrict__ W,
                     const float* __restrict__ bias, const float* __restrict__ sig,
                     float* __restrict__ out, int C, int O, int lrelu) {
    __shared__ float Ws[16][68];
    __shared__ float Xs[16][68];
    int t = threadIdx.x;
    int tx = t & 15, ty = t >> 4;
    int b = blockIdx.z;
    int n0 = blockIdx.x * 64, o0 = blockIdx.y * 64;
    float acc[4][4] = {};
    const float* xb = x + (size_t)b * C * N_PIX;
    for (int c0 = 0; c0 < C; c0 += 16) {
        #pragma unroll
        for (int i = 0; i < 4; ++i) {
            int e = t + i * 256;
            int o = e >> 4, c = e & 15;
            float wv = 0.f;
            if (o0 + o < O && c0 + c < C) wv = W[(size_t)(o0 + o) * C + c0 + c];
            Ws[c][o] = wv;
        }
        #pragma unroll
        for (int i = 0; i < 4; ++i) {
            int e = t + i * 256;
            int c = e >> 6, n = e & 63;
            float xv = 0.f;
            if (c0 + c < C) xv = xb[(size_t)(c0 + c) * N_PIX + n0 + n];
            Xs[c][n] = xv;
        }
        __syncthreads();
        #pragma unroll
        for (int cc = 0; cc < 16; ++cc) {
            float4 wv = *(const float4*)&Ws[cc][ty * 4];
            float4 xv = *(const float4*)&Xs[cc][tx * 4];
            float wa[4] = {wv.x, wv.y, wv.z, wv.w};
            float xa[4] = {xv.x, xv.y, xv.z, xv.w};
            #pragma unroll
            for (int i = 0; i < 4; ++i)
                #pragma unroll
                for (int j = 0; j < 4; ++j)
                    acc[i][j] += wa[i] * xa[j];
        }
        __syncthreads();
    }
    float ivv = sig ? sig[0] : 1.f;
    for (int i = 0; i < 4; ++i) {
        int o = o0 + ty * 4 + i;
        if (o >= O) break;
        float bv = bias[o];
        float vres[4];
        #pragma unroll
        for (int j = 0; j < 4; ++j) {
            float v = acc[i][j] * ivv + bv;
            if (lrelu) v = (v > 0.f) ? v : 0.1f * v;
            vres[j] = v;
        }
        *(float4*)&out[((size_t)b * O + o) * N_PIX + n0 + tx * 4] =
            make_float4(vres[0], vres[1], vres[2], vres[3]);
    }
}

// ---------------------------------------------------------------------------
// Transpose+split: (B,64,N) fp32 -> (B,N,128) bf16 [hi(64)|lo(64)].
// ---------------------------------------------------------------------------
__global__ __launch_bounds__(256)
void tsplit64_kernel(const float* __restrict__ in, __bf16* __restrict__ out) {
    __shared__ float tile[64 * 65];
    int t = threadIdx.x;
    int n0 = blockIdx.x * 64, b = blockIdx.y;
    for (int e = t; e < 64 * 64; e += 256) {
        int c = e >> 6, n = e & 63;
        tile[n * 65 + c] = in[((size_t)b * 64 + c) * N_PIX + n0 + n];
    }
    __syncthreads();
    for (int e = t; e < 64 * 64; e += 256) {
        int n = e >> 6, c = e & 63;
        float v = tile[n * 65 + c];
        __bf16 hi = (__bf16)v;
        size_t base = ((size_t)b * N_PIX + n0 + n) * 128;
        out[base + c] = hi;
        out[base + 64 + c] = (__bf16)(v - (float)hi);
    }
}

// ---------------------------------------------------------------------------
// Split-bf16 MFMA 1x1 conv (unchanged).
// ---------------------------------------------------------------------------
template <int WO, int WN, int MODE, int IN_F32, int LRELU>
__global__ __launch_bounds__(256)
void mfma_conv(const void* __restrict__ xt, const __bf16* __restrict__ wsp,
               const float* __restrict__ bias, float bscale,
               void* __restrict__ outp, int C, int O) {
    constexpr int NT_BLK = WN * 128;
    __shared__ __bf16 Ws[WO * 32 * 72];
    __shared__ __bf16 Xs[NT_BLK * 72];
    int t = threadIdx.x;
    int lane = t & 63, w = t >> 6;
    int l15 = lane & 15, quad = lane >> 4;
    int wo = w / WN, wn = w % WN;
    int b = blockIdx.z;
    int n0b = blockIdx.x * NT_BLK, o0b = blockIdx.y * WO * 32;

    f32x4 acc[2][8] = {};

    for (int c0 = 0; c0 < C; c0 += 32) {
        __syncthreads();
        for (int e = t; e < WO * 32 * 8; e += 256) {
            int row = e >> 3, part = e & 7;
            size_t src = (size_t)(o0b + row) * 2 * C +
                         (part < 4 ? c0 + part * 8 : C + c0 + (part - 4) * 8);
            int dst = row * 72 + (part < 4 ? part * 8 : 32 + (part - 4) * 8);
            *(uint4*)&Ws[dst] = *(const uint4*)&wsp[src];
        }
        if (IN_F32) {
            const float* xf = (const float*)xt;
            for (int e = t; e < NT_BLK * 8; e += 256) {
                int row = e >> 3, part = e & 7;
                float4 v = *(const float4*)&xf[((size_t)b * N_PIX + n0b + row) * C + c0 + part * 4];
                bf16x4v hi, lo;
                float va[4] = {v.x, v.y, v.z, v.w};
                #pragma unroll
                for (int j = 0; j < 4; ++j) {
                    hi[j] = (__bf16)va[j];
                    lo[j] = (__bf16)(va[j] - (float)hi[j]);
                }
                *(bf16x4v*)&Xs[row * 72 + part * 4] = hi;
                *(bf16x4v*)&Xs[row * 72 + 32 + part * 4] = lo;
            }
        } else {
            const __bf16* xb = (const __bf16*)xt;
            for (int e = t; e < NT_BLK * 8; e += 256) {
                int row = e >> 3, part = e & 7;
                size_t src = ((size_t)b * N_PIX + n0b + row) * 2 * C +
                             (part < 4 ? c0 + part * 8 : C + c0 + (part - 4) * 8);
                int dst = row * 72 + (part < 4 ? part * 8 : 32 + (part - 4) * 8);
                *(uint4*)&Xs[dst] = *(const uint4*)&xb[src];
            }
        }
        __syncthreads();

        bf16x8 ah[2], al[2];
        #pragma unroll
        for (int mf = 0; mf < 2; ++mf) {
            int base = (wo * 32 + mf * 16 + l15) * 72 + quad * 8;
            ah[mf] = *(const bf16x8*)&Ws[base];
            al[mf] = *(const bf16x8*)&Ws[base + 32];
        }
        #pragma unroll
        for (int nt = 0; nt < 8; ++nt) {
            int bbase = (wn * 128 + nt * 16 + l15) * 72 + quad * 8;
            bf16x8 bh = *(const bf16x8*)&Xs[bbase];
            bf16x8 bl = *(const bf16x8*)&Xs[bbase + 32];
            #pragma unroll
            for (int mf = 0; mf < 2; ++mf) {
                acc[mf][nt] = __builtin_amdgcn_mfma_f32_16x16x32_bf16(ah[mf], bh, acc[mf][nt], 0, 0, 0);
                acc[mf][nt] = __builtin_amdgcn_mfma_f32_16x16x32_bf16(ah[mf], bl, acc[mf][nt], 0, 0, 0);
                acc[mf][nt] = __builtin_amdgcn_mfma_f32_16x16x32_bf16(al[mf], bh, acc[mf][nt], 0, 0, 0);
            }
        }
    }

    float bv[2][4];
    #pragma unroll
    for (int mf = 0; mf < 2; ++mf)
        #pragma unroll
        for (int r = 0; r < 4; ++r)
            bv[mf][r] = bias[o0b + wo * 32 + mf * 16 + quad * 4 + r] * bscale;

    #pragma unroll
    for (int mf = 0; mf < 2; ++mf)
        #pragma unroll
        for (int nt = 0; nt < 8; ++nt) {
            int n = n0b + wn * 128 + nt * 16 + l15;
            float val[4];
            #pragma unroll
            for (int r = 0; r < 4; ++r) {
                float v = acc[mf][nt][r] + bv[mf][r];
                if (LRELU) v = (v > 0.f) ? v : 0.1f * v;
                val[r] = v;
            }
            int obase = o0b + wo * 32 + mf * 16 + quad * 4;
            if (MODE == 1) {
                __bf16* ob = (__bf16*)outp;
                #pragma unroll
                for (int r = 0; r < 4; ++r)
                    ob[((size_t)b * O + obase + r) * N_PIX + n] = (__bf16)val[r];
            } else if (MODE == 2) {
                __bf16* ob = (__bf16*)outp;
                bf16x4v hv, lv;
                #pragma unroll
                for (int r = 0; r < 4; ++r) {
                    hv[r] = (__bf16)val[r];
                    lv[r] = (__bf16)(val[r] - (float)hv[r]);
                }
                size_t rb = ((size_t)b * N_PIX + n) * 2 * O + obase;
                *(bf16x4v*)&ob[rb] = hv;
                *(bf16x4v*)&ob[rb + O] = lv;
            } else {  // MODE 4
                __bf16* ob = (__bf16*)outp;
                bf16x4v hv;
                #pragma unroll
                for (int r = 0; r < 4; ++r) hv[r] = (__bf16)val[r];
                *(bf16x4v*)&ob[((size_t)b * N_PIX + n) * O + obase] = hv;
            }
        }
}

// ---------------------------------------------------------------------------
// Attention kernel 1/3: S[b,q,k] raw scores (exp2-domain), bf16.
// ---------------------------------------------------------------------------
template <int CQ>
__global__ __launch_bounds__(256)
void s_gemm(const __bf16* __restrict__ qt, const __bf16* __restrict__ kt,
            __bf16* __restrict__ S) {
    constexpr int NKK = CQ / 32;
    __shared__ __bf16 Ss[128 * 136];
    int t = threadIdx.x;
    int lane = t & 63, w = t >> 6;
    int l15 = lane & 15, quad = lane >> 4;
    int k0 = blockIdx.x * 128, q0 = blockIdx.y * 128, b = blockIdx.z;

    bf16x8 kf[2][NKK], qf[8][NKK];
    #pragma unroll
    for (int mf = 0; mf < 2; ++mf)
        #pragma unroll
        for (int kk = 0; kk < NKK; ++kk)
            kf[mf][kk] = *(const bf16x8*)&kt[((size_t)b * N_PIX + k0 + w * 32 + mf * 16 + l15) * CQ + kk * 32 + quad * 8];
    #pragma unroll
    for (int nt = 0; nt < 8; ++nt)
        #pragma unroll
        for (int kk = 0; kk < NKK; ++kk)
            qf[nt][kk] = *(const bf16x8*)&qt[((size_t)b * N_PIX + q0 + nt * 16 + l15) * CQ + kk * 32 + quad * 8];

    f32x4 acc[2][8] = {};
    #pragma unroll
    for (int kk = 0; kk < NKK; ++kk)
        #pragma unroll
        for (int mf = 0; mf < 2; ++mf)
            #pragma unroll
            for (int nt = 0; nt < 8; ++nt)
                acc[mf][nt] = __builtin_amdgcn_mfma_f32_16x16x32_bf16(kf[mf][kk], qf[nt][kk], acc[mf][nt], 0, 0, 0);

    #pragma unroll
    for (int mf = 0; mf < 2; ++mf)
        #pragma unroll
        for (int nt = 0; nt < 8; ++nt) {
            bf16x4v pk;
            #pragma unroll
            for (int r = 0; r < 4; ++r) pk[r] = (__bf16)acc[mf][nt][r];
            *(bf16x4v*)&Ss[(nt * 16 + l15) * 136 + w * 32 + mf * 16 + quad * 4] = pk;
        }
    __syncthreads();
    int ql = t >> 1, kh = (t & 1) * 64;
    size_t row = ((size_t)b * N_PIX + q0 + ql) * N_PIX + k0 + kh;
    #pragma unroll
    for (int j = 0; j < 8; ++j)
        *(uint4*)&S[row + j * 8] = *(const uint4*)&Ss[ql * 136 + kh + j * 8];
}

// ---------------------------------------------------------------------------
// Attention kernel 2/3: in-place row softmax on S (exp2 domain), applied ONCE.
// One wave per 4096-key row; 4 rows/block.
// ---------------------------------------------------------------------------
__global__ __launch_bounds__(256)
void softmax_rows(__bf16* __restrict__ S) {
    int t = threadIdx.x;
    int lane = t & 63, w = t >> 6;
    __bf16* Sr = S + ((size_t)blockIdx.x * 4 + w) * N_PIX;
    bf16x8 v[8];
    #pragma unroll
    for (int j = 0; j < 8; ++j) v[j] = *(const bf16x8*)&Sr[j * 512 + lane * 8];
    float m = -1e30f;
    #pragma unroll
    for (int j = 0; j < 8; ++j)
        #pragma unroll
        for (int e = 0; e < 8; ++e) m = fmaxf(m, (float)v[j][e]);
    #pragma unroll
    for (int off = 1; off < 64; off <<= 1) m = fmaxf(m, __shfl_xor(m, off));
    float s = 0.f;
    #pragma unroll
    for (int j = 0; j < 8; ++j)
        #pragma unroll
        for (int e = 0; e < 8; ++e) {
            float p = exp2f((float)v[j][e] - m);
            s += p;
            v[j][e] = (__bf16)p;
        }
    #pragma unroll
    for (int off = 1; off < 64; off <<= 1) s += __shfl_xor(s, off);
    float il = 1.f / s;
    #pragma unroll
    for (int j = 0; j < 8; ++j) {
        #pragma unroll
        for (int e = 0; e < 8; ++e) v[j][e] = (__bf16)((float)v[j][e] * il);
        *(bf16x8*)&Sr[j * 512 + lane * 8] = v[j];
    }
}

// ---------------------------------------------------------------------------
// Attention kernel 3/3: LDS-staged PV GEMM (R9 body), grid 1024 (4 blocks/CU).
// O[b,q,c] = gamma * sum_k P[b,q,k] V[b,c,k] + residual.
// Block: 128 q x NT*16 c.  Grid 1024 = 8 cblk x 128 pair; bid%8 == pair%8
// pins all 8 c-block sharers of one (q0,b) P-slab to one XCD (L2 reuse).
// ---------------------------------------------------------------------------
template <int NT>
__global__ __launch_bounds__(256)
void pv_gemm3(const __bf16* __restrict__ P, const __bf16* __restrict__ vg,
              const __bf16* __restrict__ xin2, const float* __restrict__ gamma,
              float* __restrict__ out, int C) {
    constexpr int CCH = NT * 16;
    __shared__ __bf16 Psh[128 * 72];
    __shared__ __bf16 Vsh[CCH * 72];
    int t = threadIdx.x;
    int lane = t & 63, w = t >> 6;
    int l15 = lane & 15, quad = lane >> 4;
    int bid = blockIdx.x;
    int pair = bid & 127, cblk = bid >> 7;
    int qi = pair >> 2, b = pair & 3;
    int q0 = qi * 128, c0 = cblk * CCH;
    const __bf16* Pb = P + ((size_t)b * N_PIX + q0) * N_PIX;
    const __bf16* Vb = vg + ((size_t)b * C + c0) * N_PIX;

    f32x4 acc[2][NT] = {};

    for (int k0 = 0; k0 < N_PIX; k0 += 64) {
        __syncthreads();
        #pragma unroll
        for (int i = 0; i < 4; ++i) {  // P tile: 128 q-rows x 64 k
            int e = t + i * 256;
            int row = e >> 3, seg = e & 7;
            *(uint4*)&Psh[row * 72 + seg * 8] = *(const uint4*)&Pb[(size_t)row * N_PIX + k0 + seg * 8];
        }
        for (int e = t; e < CCH * 8; e += 256) {  // V tile: CCH c-rows x 64 k
            int row = e >> 3, seg = e & 7;
            *(uint4*)&Vsh[row * 72 + seg * 8] = *(const uint4*)&Vb[(size_t)row * N_PIX + k0 + seg * 8];
        }
        __syncthreads();
        #pragma unroll
        for (int kk = 0; kk < 2; ++kk) {
            bf16x8 pa[2];
            #pragma unroll
            for (int mf = 0; mf < 2; ++mf)
                pa[mf] = *(const bf16x8*)&Psh[(w * 32 + mf * 16 + l15) * 72 + kk * 32 + quad * 8];
            #pragma unroll
            for (int nt = 0; nt < NT; ++nt) {
                bf16x8 vf = *(const bf16x8*)&Vsh[(nt * 16 + l15) * 72 + kk * 32 + quad * 8];
                #pragma unroll
                for (int mf = 0; mf < 2; ++mf)
                    acc[mf][nt] = __builtin_amdgcn_mfma_f32_16x16x32_bf16(pa[mf], vf, acc[mf][nt], 0, 0, 0);
            }
        }
    }

    float g = gamma[0];
    #pragma unroll
    for (int mf = 0; mf < 2; ++mf)
        #pragma unroll
        for (int r = 0; r < 4; ++r) {
            int q = q0 + w * 32 + mf * 16 + quad * 4 + r;
            size_t xrb = ((size_t)b * N_PIX + q) * 2 * C;
            size_t orb = ((size_t)b * N_PIX + q) * C;
            #pragma unroll
            for (int nt = 0; nt < NT; ++nt) {
                int c = c0 + nt * 16 + l15;
                float xr = (float)xin2[xrb + c] + (float)xin2[xrb + C + c];
                out[orb + c] = g * acc[mf][nt][r] + xr;
            }
        }
}

// ---------------------------------------------------------------------------
// L5: out[b,n] = lrelu(iv * dot(W5, h[b,n,:]) + b5).  h: (B,N,512) fp32.
// ---------------------------------------------------------------------------
__global__ __launch_bounds__(256)
void l5_kernel(const float* __restrict__ h, const float* __restrict__ W5,
               const float* __restrict__ b5, const float* __restrict__ sig,
               float* __restrict__ out) {
    int t = threadIdx.x;
    int lane = t & 63, w = t >> 6;
    int p = blockIdx.x * 4 + w;
    const float* row = h + (size_t)p * 512;
    float4 a0 = *(const float4*)&row[lane * 8];
    float4 a1 = *(const float4*)&row[lane * 8 + 4];
    float4 w0 = *(const float4*)&W5[lane * 8];
    float4 w1 = *(const float4*)&W5[lane * 8 + 4];
    float s = a0.x * w0.x + a0.y * w0.y + a0.z * w0.z + a0.w * w0.w +
              a1.x * w1.x + a1.y * w1.y + a1.z * w1.z + a1.w * w1.w;
    #pragma unroll
    for (int off = 1; off < 64; off <<= 1) s += __shfl_xor(s, off);
    if (lane == 0) {
        float v = sig[0] * s + b5[0];
        out[p] = (v > 0.f) ? v : 0.1f * v;
    }
}

// ---------------------------------------------------------------------------
// Launcher
// ---------------------------------------------------------------------------
extern "C" void kernel_launch(void* const* d_in, const int* in_sizes, int n_in,
                              void* d_out, int out_size, void* d_ws, size_t ws_size,
                              hipStream_t stream) {
    const float* x   = (const float*)d_in[0];
    const float* W1  = (const float*)d_in[1];
    const float* b1  = (const float*)d_in[2];
    const float* u1  = (const float*)d_in[3];
    const float* W2  = (const float*)d_in[4];
    const float* b2  = (const float*)d_in[5];
    const float* u2  = (const float*)d_in[6];
    const float* W3  = (const float*)d_in[7];
    const float* b3  = (const float*)d_in[8];
    const float* u3  = (const float*)d_in[9];
    const float* W4  = (const float*)d_in[10];
    const float* b4  = (const float*)d_in[11];
    const float* u4  = (const float*)d_in[12];
    const float* W5  = (const float*)d_in[13];
    const float* b5  = (const float*)d_in[14];
    const float* u5  = (const float*)d_in[15];
    const float* a1_qW = (const float*)d_in[16];
    const float* a1_qb = (const float*)d_in[17];
    const float* a1_kW = (const float*)d_in[18];
    const float* a1_kb = (const float*)d_in[19];
    const float* a1_vW = (const float*)d_in[20];
    const float* a1_vb = (const float*)d_in[21];
    const float* a1_g  = (const float*)d_in[22];
    const float* a2_qW = (const float*)d_in[23];
    const float* a2_qb = (const float*)d_in[24];
    const float* a2_kW = (const float*)d_in[25];
    const float* a2_kb = (const float*)d_in[26];
    const float* a2_vW = (const float*)d_in[27];
    const float* a2_vb = (const float*)d_in[28];
    const float* a2_g  = (const float*)d_in[29];

    float* ws = (float*)d_ws;
    const size_t NF = (size_t)BATCH * N_PIX;  // 16384
    float* sig    = ws;                       // 16
    float* h1     = ws + 16;                  // NF*64 fl
    float* slabC  = h1 + NF * 64;             // NF*512 fl
    float* slabS1 = slabC + NF * 512;         // NF*256 fl
    float* slabS2 = slabS1 + NF * 256;        // NF*512 fl
    float* qtf    = slabS2 + NF * 512;        // NF*32 fl
    float* ktf    = qtf + NF * 32;            // NF*32 fl
    float* wspf   = ktf + NF * 32;            // ~0.58M fl
    float* Sf     = wspf + 600000;            // S: NF*4096 bf16 = NF*2048 fl

    __bf16* h1t = (__bf16*)slabS1;            // (B,N,128)
    __bf16* h2t = (__bf16*)slabS2;            // (B,N,256)
    __bf16* h3t = (__bf16*)slabS1;            // (B,N,512)
    __bf16* h5t = (__bf16*)slabS2;            // (B,N,1024)
    float*  h4t = slabC;                      // (B,N,256) fp32
    __bf16* vb1 = (__bf16*)(slabC + NF * 256);// (B,256,N)
    float*  h6t = slabC;                      // (B,N,512) fp32
    __bf16* vb2 = (__bf16*)slabS1;            // (B,512,N)
    __bf16* qt  = (__bf16*)qtf;
    __bf16* ktb = (__bf16*)ktf;
    __bf16* wsp = (__bf16*)wspf;
    __bf16* Sbuf = (__bf16*)Sf;               // (B,4096,4096) bf16

    __bf16* wsL2  = wsp;            // 128*128
    __bf16* wsL3  = wsL2 + 16384;   // 256*256
    __bf16* wsL4  = wsL3 + 65536;   // 512*512
    __bf16* wsA1q = wsL4 + 262144;  // 32*512
    __bf16* wsA1k = wsA1q + 16384;
    __bf16* wsA1v = wsA1k + 16384;  // 256*512
    __bf16* wsA2q = wsA1v + 131072; // 64*1024
    __bf16* wsA2k = wsA2q + 65536;
    __bf16* wsA2v = wsA2k + 65536;  // 512*1024

    dim3 blk(256);

    SigP sp;
    sp.W[0] = W1; sp.u[0] = u1; sp.O[0] = 64;  sp.C[0] = 6;
    sp.W[1] = W2; sp.u[1] = u2; sp.O[1] = 128; sp.C[1] = 64;
    sp.W[2] = W3; sp.u[2] = u3; sp.O[2] = 256; sp.C[2] = 128;
    sp.W[3] = W4; sp.u[3] = u4; sp.O[3] = 512; sp.C[3] = 256;
    sp.W[4] = W5; sp.u[4] = u5; sp.O[4] = 1;   sp.C[4] = 512;
    sigma_all<<<dim3(5), dim3(1024), 0, stream>>>(sp, sig);

    wsplit_kernel<<<128, blk, 0, stream>>>(W2, sig + 1, 1.f, 64, wsL2);
    wsplit_kernel<<<256, blk, 0, stream>>>(W3, sig + 2, 1.f, 128, wsL3);
    wsplit_kernel<<<512, blk, 0, stream>>>(W4, sig + 3, 1.f, 256, wsL4);
    wsplit_kernel<<<32,  blk, 0, stream>>>(a1_qW, nullptr, LOG2E, 256, wsA1q);
    wsplit_kernel<<<32,  blk, 0, stream>>>(a1_kW, nullptr, 1.f, 256, wsA1k);
    wsplit_kernel<<<256, blk, 0, stream>>>(a1_vW, nullptr, 1.f, 256, wsA1v);
    wsplit_kernel<<<64,  blk, 0, stream>>>(a2_qW, nullptr, LOG2E, 512, wsA2q);
    wsplit_kernel<<<64,  blk, 0, stream>>>(a2_kW, nullptr, 1.f, 512, wsA2k);
    wsplit_kernel<<<512, blk, 0, stream>>>(a2_vW, nullptr, 1.f, 512, wsA2v);

    // L1 (fp32) + transpose/split
    conv_f32_kernel<<<dim3(64, 1, 4), blk, 0, stream>>>(x, W1, b1, sig + 0, h1, 6, 64, 1);
    tsplit64_kernel<<<dim3(64, 4), blk, 0, stream>>>(h1, h1t);

    // L2, L3 (split-MFMA)
    mfma_conv<4, 1, 2, 0, 1><<<dim3(32, 1, 4), blk, 0, stream>>>(h1t, wsL2, b2, 1.f, h2t, 64, 128);
    mfma_conv<4, 1, 2, 0, 1><<<dim3(32, 2, 4), blk, 0, stream>>>(h2t, wsL3, b3, 1.f, h3t, 128, 256);

    // attention 1 (C=256, Cq=32)
    mfma_conv<1, 4, 4, 0, 0><<<dim3(8, 1, 4), blk, 0, stream>>>(h3t, wsA1q, a1_qb, LOG2E, qt, 256, 32);
    mfma_conv<1, 4, 4, 0, 0><<<dim3(8, 1, 4), blk, 0, stream>>>(h3t, wsA1k, a1_kb, 1.f, ktb, 256, 32);
    mfma_conv<4, 1, 1, 0, 0><<<dim3(32, 2, 4), blk, 0, stream>>>(h3t, wsA1v, a1_vb, 1.f, vb1, 256, 256);
    s_gemm<32><<<dim3(32, 32, 4), blk, 0, stream>>>(qt, ktb, Sbuf);
    softmax_rows<<<dim3(4096), blk, 0, stream>>>(Sbuf);
    pv_gemm3<2><<<dim3(1024), blk, 0, stream>>>(Sbuf, vb1, h3t, a1_g, h4t, 256);

    // L4 (fp32-transposed input)
    mfma_conv<4, 1, 2, 1, 1><<<dim3(32, 4, 4), blk, 0, stream>>>(h4t, wsL4, b4, 1.f, h5t, 256, 512);

    // attention 2 (C=512, Cq=64)
    mfma_conv<2, 2, 4, 0, 0><<<dim3(16, 1, 4), blk, 0, stream>>>(h5t, wsA2q, a2_qb, LOG2E, qt, 512, 64);
    mfma_conv<2, 2, 4, 0, 0><<<dim3(16, 1, 4), blk, 0, stream>>>(h5t, wsA2k, a2_kb, 1.f, ktb, 512, 64);
    mfma_conv<4, 1, 1, 0, 0><<<dim3(32, 4, 4), blk, 0, stream>>>(h5t, wsA2v, a2_vb, 1.f, vb2, 512, 512);
    s_gemm<64><<<dim3(32, 32, 4), blk, 0, stream>>>(qt, ktb, Sbuf);
    softmax_rows<<<dim3(4096), blk, 0, stream>>>(Sbuf);
    pv_gemm3<4><<<dim3(1024), blk, 0, stream>>>(Sbuf, vb2, h5t, a2_g, h6t, 512);

    // L5
    l5_kernel<<<4096, blk, 0, stream>>>(h6t, W5, b5, sig + 4, (float*)d_out);
}